// Round 1
// baseline (1234.226 us; speedup 1.0000x reference)
//
#include <hip/hip_runtime.h>

// Bidirectional LSTM, I=7, H=64, O=3, B=256, T=2048.
// Output = concat(h_fwd after T steps, h_bwd after ONE step on x[T-1]) @ W_lin^T + b_lin.
// One block per batch element (256 blocks ~ 1/CU), 256 threads = 4 waves.
// Thread g owns gate-row g: W_hh row (64 regs), W_ih row (7 regs), bias.
// Per step: z_g = bias + W_ih.x_t + W_hh.h  (h via LDS broadcast reads),
// gate activations -> zs[t&1][g], ONE barrier, then every wave redundantly
// updates c (lane-private reg) and h (per-wave LDS copy) -> no 2nd barrier.

#define TSEQ 2048
#define IN   7
#define HID  64
#define G4   256

__device__ __forceinline__ float fast_sigmoid(float x) {
    return 1.0f / (1.0f + __expf(-x));
}
__device__ __forceinline__ float fast_tanh(float x) {
    x = fminf(15.0f, fmaxf(-15.0f, x));   // avoid inf/inf for large |c|
    float e = __expf(2.0f * x);
    return (e - 1.0f) / (e + 1.0f);
}

__global__ __launch_bounds__(256, 1)
void bilstm_kernel(const float* __restrict__ x,      // [B, T, I]
                   const float* __restrict__ Wih_f,  // [256, 7]
                   const float* __restrict__ Whh_f,  // [256, 64]
                   const float* __restrict__ bih_f,  // [256]
                   const float* __restrict__ bhh_f,  // [256]
                   const float* __restrict__ Wih_b,  // [256, 7]
                   const float* __restrict__ bih_b,  // [256]
                   const float* __restrict__ bhh_b,  // [256]
                   const float* __restrict__ Wlin,   // [3, 128]
                   const float* __restrict__ blin,   // [3]
                   float* __restrict__ out)          // [B, 3]
{
    __shared__ __align__(16) float xs[TSEQ * IN];   // 57344 B: whole sequence for this batch elem
    __shared__ __align__(16) float zs[2][G4];       // double-buffered gate activations
    __shared__ __align__(16) float hs[4][HID];      // per-wave private h copy
    __shared__ __align__(16) float hbs[HID];        // backward one-step h

    const int tid  = threadIdx.x;
    const int lane = tid & 63;
    const int wv   = tid >> 6;
    const int cls  = tid >> 6;        // gate class: 0=i 1=f 2=g 3=o
    const int b    = blockIdx.x;

    // ---- stage x for this batch element into LDS (coalesced) ----
    const float* xb = x + (size_t)b * (TSEQ * IN);
    for (int i = tid; i < TSEQ * IN; i += 256) xs[i] = xb[i];

    // ---- per-thread weights in registers ----
    float wih[IN];
    #pragma unroll
    for (int i = 0; i < IN; ++i) wih[i] = Wih_f[tid * IN + i];
    const float bias = bih_f[tid] + bhh_f[tid];

    float4 whh[16];
    const float4* wr = (const float4*)(Whh_f + tid * HID);
    #pragma unroll
    for (int j = 0; j < 16; ++j) whh[j] = wr[j];

    hs[wv][lane] = 0.0f;   // each wave zeros its own h copy (all 64 lanes)
    float c = 0.0f;        // lane-private cell state (replicated per wave)
    __syncthreads();

    // ---- forward recurrence ----
    for (int t = 0; t < TSEQ; ++t) {
        const int p = t & 1;
        const float* xp = &xs[t * IN];
        const float4* h4 = (const float4*)hs[wv];

        // 4 independent accumulator chains for ILP (1 wave/SIMD -> latency exposed)
        float z0 = fmaf(xp[0], wih[0], fmaf(xp[1], wih[1], bias));
        float z1 = fmaf(xp[2], wih[2], xp[3] * wih[3]);
        float z2 = fmaf(xp[4], wih[4], xp[5] * wih[5]);
        float z3 = xp[6] * wih[6];

        #pragma unroll
        for (int j = 0; j < 16; j += 4) {
            float4 h0 = h4[j + 0], h1 = h4[j + 1], h2 = h4[j + 2], h3 = h4[j + 3];
            z0 = fmaf(h0.x, whh[j+0].x, fmaf(h0.y, whh[j+0].y, fmaf(h0.z, whh[j+0].z, fmaf(h0.w, whh[j+0].w, z0))));
            z1 = fmaf(h1.x, whh[j+1].x, fmaf(h1.y, whh[j+1].y, fmaf(h1.z, whh[j+1].z, fmaf(h1.w, whh[j+1].w, z1))));
            z2 = fmaf(h2.x, whh[j+2].x, fmaf(h2.y, whh[j+2].y, fmaf(h2.z, whh[j+2].z, fmaf(h2.w, whh[j+2].w, z2))));
            z3 = fmaf(h3.x, whh[j+3].x, fmaf(h3.y, whh[j+3].y, fmaf(h3.z, whh[j+3].z, fmaf(h3.w, whh[j+3].w, z3))));
        }
        const float zv = (z0 + z1) + (z2 + z3);
        const float a  = (cls == 2) ? fast_tanh(zv) : fast_sigmoid(zv);
        zs[p][tid] = a;
        __syncthreads();   // the ONLY barrier per step (zs is double-buffered)

        // redundant update in every wave: lane l owns c[l]; h -> own wave's LDS copy
        const float zi = zs[p][lane];
        const float zf = zs[p][64 + lane];
        const float zg = zs[p][128 + lane];
        const float zo = zs[p][192 + lane];
        c = fmaf(zf, c, zi * zg);
        hs[wv][lane] = zo * fast_tanh(c);
        // no barrier: next iteration reads this wave's own copy (in-wave lgkmcnt ordering)
    }

    // ---- backward direction: exactly ONE step on x[T-1] from zero state ----
    float wib[IN];
    #pragma unroll
    for (int i = 0; i < IN; ++i) wib[i] = Wih_b[tid * IN + i];
    const float biasb = bih_b[tid] + bhh_b[tid];
    const float* xl = &xs[(TSEQ - 1) * IN];
    float zb = biasb;
    #pragma unroll
    for (int i = 0; i < IN; ++i) zb = fmaf(xl[i], wib[i], zb);
    const float ab = (cls == 2) ? fast_tanh(zb) : fast_sigmoid(zb);
    __syncthreads();           // make sure last-step zs reads are done before overwrite
    zs[0][tid] = ab;
    __syncthreads();

    if (tid < HID) {
        const float zi = zs[0][tid];
        const float zg = zs[0][128 + tid];
        const float zo = zs[0][192 + tid];
        const float cb = zi * zg;          // c0 = 0 -> f*c0 vanishes
        hbs[tid] = zo * fast_tanh(cb);
    }
    __syncthreads();

    // ---- final linear: out[b][o] = b_lin[o] + hf . Wlin[o][0:64] + hb . Wlin[o][64:128]
    if (tid < 3) {
        const float* wl = Wlin + tid * 128;
        float s = blin[tid];
        #pragma unroll 8
        for (int j = 0; j < HID; ++j) s = fmaf(hs[0][j], wl[j], s);
        #pragma unroll 8
        for (int j = 0; j < HID; ++j) s = fmaf(hbs[j], wl[64 + j], s);
        out[b * 3 + tid] = s;
    }
}

extern "C" void kernel_launch(void* const* d_in, const int* in_sizes, int n_in,
                              void* d_out, int out_size, void* d_ws, size_t ws_size,
                              hipStream_t stream) {
    const float* x      = (const float*)d_in[0];
    const float* Wih_f  = (const float*)d_in[1];
    const float* Whh_f  = (const float*)d_in[2];
    const float* bih_f  = (const float*)d_in[3];
    const float* bhh_f  = (const float*)d_in[4];
    const float* Wih_b  = (const float*)d_in[5];
    // d_in[6] = W_hh_bwd: unused (backward runs exactly one step from h0=0)
    const float* bih_b  = (const float*)d_in[7];
    const float* bhh_b  = (const float*)d_in[8];
    const float* Wlin   = (const float*)d_in[9];
    const float* blin   = (const float*)d_in[10];
    float* out = (float*)d_out;

    bilstm_kernel<<<256, 256, 0, stream>>>(x, Wih_f, Whh_f, bih_f, bhh_f,
                                           Wih_b, bih_b, bhh_b, Wlin, blin, out);
}

// Round 2
// 1163.816 us; speedup vs baseline: 1.0605x; 1.0605x over previous
//
#include <hip/hip_runtime.h>

// Bidirectional LSTM, I=7, H=64, O=3, B=256, T=2048.
// Output = concat(h_fwd after T steps, h_bwd after ONE step on x[T-1]) @ W_lin^T + b_lin.
// One block per batch element (256 blocks ~ 1/CU), 256 threads = 4 waves.
//
// Round-2 change (theory: round-1 was LDS-throughput-bound on 64x ds_read_b128
// broadcast of h per CU per step): h now lives ONLY in registers. Every wave
// redundantly updates h (lane l owns h[l]); the W_hh.h dot product broadcasts
// h via v_readlane -> SGPR and v_fmac with SGPR operand. Zero LDS traffic for h.
// Per step: A) z_g = bias + W_ih.x_t + W_hh.h (readlane broadcast), activation,
// write zs[p][g]; ONE barrier; C) each wave redundantly updates c (lane-private
// reg) and h (lane-private reg) from 4 zs reads. zs double-buffered -> 1 barrier.

#define TSEQ 2048
#define IN   7

__device__ __forceinline__ float fast_sigmoid(float x) {
    return 1.0f / (1.0f + __expf(-x));
}
__device__ __forceinline__ float fast_tanh(float x) {
    x = fminf(15.0f, fmaxf(-15.0f, x));   // avoid inf/inf for large |c|
    float e = __expf(2.0f * x);
    return (e - 1.0f) / (e + 1.0f);
}
// broadcast lane k of v to all lanes as a wave-uniform scalar (v_readlane -> SGPR)
__device__ __forceinline__ float bcast(float v, int k) {
    return __uint_as_float(__builtin_amdgcn_readlane(__float_as_uint(v), k));
}

__global__ __launch_bounds__(256, 1)
void bilstm_kernel(const float* __restrict__ x,      // [B, T, I]
                   const float* __restrict__ Wih_f,  // [256, 7]
                   const float* __restrict__ Whh_f,  // [256, 64]
                   const float* __restrict__ bih_f,  // [256]
                   const float* __restrict__ bhh_f,  // [256]
                   const float* __restrict__ Wih_b,  // [256, 7]
                   const float* __restrict__ bih_b,  // [256]
                   const float* __restrict__ bhh_b,  // [256]
                   const float* __restrict__ Wlin,   // [3, 128]
                   const float* __restrict__ blin,   // [3]
                   float* __restrict__ out)          // [B, 3]
{
    __shared__ __align__(16) float xs[TSEQ * IN];   // 57344 B: whole sequence for this batch elem
    __shared__ __align__(16) float zs[2][256];      // double-buffered gate activations
    __shared__ __align__(16) float hf[64];          // forward final h (written once at end)
    __shared__ __align__(16) float hbs[64];         // backward one-step h

    const int tid  = threadIdx.x;
    const int lane = tid & 63;
    const int cls  = tid >> 6;        // gate class: 0=i 1=f 2=g 3=o (wave-uniform)
    const int b    = blockIdx.x;

    // ---- stage x for this batch element into LDS (coalesced) ----
    const float* xb = x + (size_t)b * (TSEQ * IN);
    for (int i = tid; i < TSEQ * IN; i += 256) xs[i] = xb[i];

    // ---- per-thread weights in registers ----
    float wih[IN];
    #pragma unroll
    for (int i = 0; i < IN; ++i) wih[i] = Wih_f[tid * IN + i];
    const float bias = bih_f[tid] + bhh_f[tid];

    float4 whh[16];
    const float4* wr = (const float4*)(Whh_f + tid * 64);
    #pragma unroll
    for (int j = 0; j < 16; ++j) whh[j] = wr[j];

    float h = 0.0f;        // lane l owns h[l]; replicated in every wave
    float c = 0.0f;        // lane l owns c[l]; replicated in every wave
    __syncthreads();

    // ---- forward recurrence ----
    for (int t = 0; t < TSEQ; ++t) {
        const int p = t & 1;
        const float* xp = &xs[t * IN];

        // input projection: 4 independent accumulator chains
        float z0 = fmaf(xp[0], wih[0], fmaf(xp[1], wih[1], bias));
        float z1 = fmaf(xp[2], wih[2], xp[3] * wih[3]);
        float z2 = fmaf(xp[4], wih[4], xp[5] * wih[5]);
        float z3 = xp[6] * wih[6];

        // W_hh . h via register broadcast (v_readlane), no LDS
        #pragma unroll
        for (int k = 0; k < 64; k += 4) {
            const float h0 = bcast(h, k + 0);
            const float h1 = bcast(h, k + 1);
            const float h2 = bcast(h, k + 2);
            const float h3 = bcast(h, k + 3);
            const float4 w = whh[k >> 2];
            z0 = fmaf(h0, w.x, z0);
            z1 = fmaf(h1, w.y, z1);
            z2 = fmaf(h2, w.z, z2);
            z3 = fmaf(h3, w.w, z3);
        }
        const float zv = (z0 + z1) + (z2 + z3);
        const float a  = (cls == 2) ? fast_tanh(zv) : fast_sigmoid(zv);
        zs[p][tid] = a;
        __syncthreads();   // the ONLY barrier per step (zs is double-buffered)

        // redundant update in every wave: lane l owns c[l], h[l] in registers
        const float zi = zs[p][lane];
        const float zf = zs[p][64 + lane];
        const float zg = zs[p][128 + lane];
        const float zo = zs[p][192 + lane];
        c = fmaf(zf, c, zi * zg);
        h = zo * fast_tanh(c);
        // no barrier: everything needed next step is in-wave registers
    }

    // publish forward final h once (wave 0's copy; all copies identical)
    if (tid < 64) hf[tid] = h;

    // ---- backward direction: exactly ONE step on x[T-1] from zero state ----
    float wib[IN];
    #pragma unroll
    for (int i = 0; i < IN; ++i) wib[i] = Wih_b[tid * IN + i];
    const float biasb = bih_b[tid] + bhh_b[tid];
    const float* xl = &xs[(TSEQ - 1) * IN];
    float zb = biasb;
    #pragma unroll
    for (int i = 0; i < IN; ++i) zb = fmaf(xl[i], wib[i], zb);
    const float ab = (cls == 2) ? fast_tanh(zb) : fast_sigmoid(zb);
    __syncthreads();           // last-step zs reads done before overwrite
    zs[0][tid] = ab;
    __syncthreads();

    if (tid < 64) {
        const float zi = zs[0][tid];
        const float zg = zs[0][128 + tid];
        const float zo = zs[0][192 + tid];
        const float cb = zi * zg;          // c0 = 0 -> f*c0 vanishes
        hbs[tid] = zo * fast_tanh(cb);
    }
    __syncthreads();

    // ---- final linear: out[b][o] = b_lin[o] + hf . Wlin[o][0:64] + hb . Wlin[o][64:128]
    if (tid < 3) {
        const float* wl = Wlin + tid * 128;
        float s = blin[tid];
        #pragma unroll 8
        for (int j = 0; j < 64; ++j) s = fmaf(hf[j], wl[j], s);
        #pragma unroll 8
        for (int j = 0; j < 64; ++j) s = fmaf(hbs[j], wl[64 + j], s);
        out[b * 3 + tid] = s;
    }
}

extern "C" void kernel_launch(void* const* d_in, const int* in_sizes, int n_in,
                              void* d_out, int out_size, void* d_ws, size_t ws_size,
                              hipStream_t stream) {
    const float* x      = (const float*)d_in[0];
    const float* Wih_f  = (const float*)d_in[1];
    const float* Whh_f  = (const float*)d_in[2];
    const float* bih_f  = (const float*)d_in[3];
    const float* bhh_f  = (const float*)d_in[4];
    const float* Wih_b  = (const float*)d_in[5];
    // d_in[6] = W_hh_bwd: unused (backward runs exactly one step from h0=0)
    const float* bih_b  = (const float*)d_in[7];
    const float* bhh_b  = (const float*)d_in[8];
    const float* Wlin   = (const float*)d_in[9];
    const float* blin   = (const float*)d_in[10];
    float* out = (float*)d_out;

    bilstm_kernel<<<256, 256, 0, stream>>>(x, Wih_f, Whh_f, bih_f, bhh_f,
                                           Wih_b, bih_b, bhh_b, Wlin, blin, out);
}